// Round 1
// baseline (2171.136 us; speedup 1.0000x reference)
//
#include <hip/hip_runtime.h>
#include <hip/hip_bf16.h>
#include <cmath>

// Problem constants (from reference setup_inputs)
#define B       64
#define IN_PN   20000
#define OUT_PN  5000
#define MM      9
#define CIN     32
#define COUT    64
#define XS_STRIDE  36   // 32 + 4 pad: bank = 4*(b+c4) % 32 -> full-rate b128 LDS
#define OUT_STRIDE 68   // 64 + 4 pad for epilogue transpose

// One block per output point p. 256 threads = 4 waves.
// Compute map: b = tid&63 (batch), og = tid>>6 (o-group of 16 outputs).
// W reads from LDS are wave-uniform (broadcast); X reads are lane-distinct,
// conflict-free via stride-36 pad.
__global__ __launch_bounds__(256, 4) void pconv_kernel(
    const float* __restrict__ in_pc,       // (B, IN_PN, CIN)
    const int*   __restrict__ neighbor_id, // (OUT_PN, M)
    const float* __restrict__ weights,     // (OUT_PN, M, COUT, CIN)
    const float* __restrict__ bias,        // (OUT_PN, COUT)
    const float* __restrict__ p_neighbors, // (OUT_PN, M)
    const float* __restrict__ weight_res,  // (COUT, CIN)
    float*       __restrict__ out)         // (B, OUT_PN, COUT)
{
    __shared__ float smem[64 * XS_STRIDE + COUT * CIN]; // 2304 + 2048 = 4352 floats
    float* Xs = smem;                 // [64][36]
    float* Ws = smem + 64 * XS_STRIDE; // [64][32]

    const int p  = blockIdx.x;
    const int t  = threadIdx.x;
    const int b  = t & 63;   // compute: batch row
    const int og = t >> 6;   // compute: output group (0..3), 16 outputs each
    const int bb = t >> 2;   // staging: row
    const int q  = t & 3;    // staging: quarter of a 32-float row

    // ---- neighbor ids + normalized residual weights (wave-uniform) ----
    int   nid[MM];
    float pn[MM];
    float psum = 0.f;
#pragma unroll
    for (int m = 0; m < MM; ++m) {
        nid[m] = neighbor_id[p * MM + m];
        float pv = fabsf(p_neighbors[p * MM + m]);
        pv = (nid[m] != IN_PN) ? pv : 0.f;
        pn[m] = pv;
        psum += pv;
    }
    const float pinv = 1.f / (psum + 1e-8f);
#pragma unroll
    for (int m = 0; m < MM; ++m) pn[m] *= pinv;

    float acc[16];
#pragma unroll
    for (int j = 0; j < 16; ++j) acc[j] = 0.f;
    float rv[8];
#pragma unroll
    for (int i = 0; i < 8; ++i) rv[i] = 0.f;

    // ---- main m-loop: stage X_m (gather) + W_m, then 64x64x32 FMA tile ----
    for (int m = 0; m < MM; ++m) {
        const int n = nid[m];
        float4 a0, a1;
        if (n != IN_PN) {
            const float* src = in_pc + ((size_t)bb * IN_PN + (size_t)n) * CIN;
            a0 = *(const float4*)(src + q * 4);
            a1 = *(const float4*)(src + 16 + q * 4);
        } else {
            a0 = make_float4(0.f, 0.f, 0.f, 0.f);
            a1 = a0;
        }
        *(float4*)&Xs[bb * XS_STRIDE + q * 4]      = a0;
        *(float4*)&Xs[bb * XS_STRIDE + 16 + q * 4] = a1;

        const float* wsrc = weights + ((size_t)p * MM + m) * (COUT * CIN);
        *(float4*)&Ws[t * 4]        = *(const float4*)(wsrc + t * 4);
        *(float4*)&Ws[1024 + t * 4] = *(const float4*)(wsrc + 1024 + t * 4);
        __syncthreads();

        float4 xv[8];
#pragma unroll
        for (int c4 = 0; c4 < 8; ++c4)
            xv[c4] = *(const float4*)&Xs[b * XS_STRIDE + c4 * 4];

        // residual accumulation rides for free on xv (this thread owns c = og*8..og*8+7)
        const float pm = pn[m];
#pragma unroll
        for (int i = 0; i < 2; ++i) {
            float4 x = xv[og * 2 + i];
            rv[i * 4 + 0] += pm * x.x;
            rv[i * 4 + 1] += pm * x.y;
            rv[i * 4 + 2] += pm * x.z;
            rv[i * 4 + 3] += pm * x.w;
        }

#pragma unroll
        for (int j = 0; j < 16; ++j) {
            const int o = og * 16 + j;
            float s = acc[j];
#pragma unroll
            for (int c4 = 0; c4 < 8; ++c4) {
                float4 w = *(const float4*)&Ws[o * CIN + c4 * 4]; // wave-uniform -> broadcast
                s += xv[c4].x * w.x;
                s += xv[c4].y * w.y;
                s += xv[c4].z * w.z;
                s += xv[c4].w * w.w;
            }
            acc[j] = s;
        }
        __syncthreads();
    }

    // ---- residual GEMM: Rs(64x32) . weight_res(64x32)^T ----
    *(float4*)&Xs[b * XS_STRIDE + og * 8]     = make_float4(rv[0], rv[1], rv[2], rv[3]);
    *(float4*)&Xs[b * XS_STRIDE + og * 8 + 4] = make_float4(rv[4], rv[5], rv[6], rv[7]);
    *(float4*)&Ws[t * 4]        = *(const float4*)(weight_res + t * 4);
    *(float4*)&Ws[1024 + t * 4] = *(const float4*)(weight_res + 1024 + t * 4);
    __syncthreads();

    float4 xv[8];
#pragma unroll
    for (int c4 = 0; c4 < 8; ++c4)
        xv[c4] = *(const float4*)&Xs[b * XS_STRIDE + c4 * 4];

    float outv[16];
#pragma unroll
    for (int j = 0; j < 16; ++j) {
        const int o = og * 16 + j;
        float r = 0.f;
#pragma unroll
        for (int c4 = 0; c4 < 8; ++c4) {
            float4 w = *(const float4*)&Ws[o * CIN + c4 * 4];
            r += xv[c4].x * w.x + xv[c4].y * w.y + xv[c4].z * w.z + xv[c4].w * w.w;
        }
        float cv = acc[j] + bias[p * COUT + o];
        cv = (cv > 0.f) ? cv : expm1f(cv);          // jax.nn.elu = where(x>0, x, expm1(x))
        outv[j] = 0.70710678118654752f * (cv + r);  // sqrt(1-RR) == sqrt(RR) == sqrt(0.5)
    }
    __syncthreads(); // all reads of Xs/Ws done; smem becomes the transpose buffer

    // ---- epilogue transpose for coalesced 256B-contiguous stores ----
#pragma unroll
    for (int j = 0; j < 16; ++j)
        smem[b * OUT_STRIDE + og * 16 + j] = outv[j];
    __syncthreads();

#pragma unroll
    for (int s = 0; s < 4; ++s) {
        float4 v = *(const float4*)&smem[bb * OUT_STRIDE + q * 16 + s * 4];
        *(float4*)&out[((size_t)bb * OUT_PN + (size_t)p) * COUT + q * 16 + s * 4] = v;
    }
}

extern "C" void kernel_launch(void* const* d_in, const int* in_sizes, int n_in,
                              void* d_out, int out_size, void* d_ws, size_t ws_size,
                              hipStream_t stream) {
    const float* in_pc       = (const float*)d_in[0];
    const int*   neighbor_id = (const int*)d_in[1];
    const float* weights     = (const float*)d_in[2];
    const float* bias        = (const float*)d_in[3];
    const float* p_neighbors = (const float*)d_in[4];
    const float* weight_res  = (const float*)d_in[5];
    float*       out         = (float*)d_out;

    pconv_kernel<<<OUT_PN, 256, 0, stream>>>(in_pc, neighbor_id, weights, bias,
                                             p_neighbors, weight_res, out);
}